// Round 3
// baseline (1111.279 us; speedup 1.0000x reference)
//
#include <hip/hip_runtime.h>
#include <math.h>

#define BB 8
#define NN 2048
#define DD 256
#define KNN 8
#define NPTS (BB*NN)        // 16384
#define NEDGE (NPTS*KNN)    // 131072
#define BN_EPS 1e-5f
#define NSH 64              // shadow copies for stats accumulation (atomic decontention)

// ---- workspace layout (float offsets) ----
#define OFF_X      0
#define OFF_FEAT   (OFF_X + NPTS*DD)
#define OFF_SQ     (OFF_FEAT + NPTS*3*DD)
#define OFF_IDX    (OFF_SQ + NPTS)
#define OFF_U      (OFF_IDX + NEDGE)
#define OFF_V      (OFF_U + NPTS*DD)
#define OFF_WU     (OFF_V + NPTS*DD)
#define OFF_W2P    (OFF_WU + DD*DD)
#define OFF_BIASP  (OFF_W2P + DD*DD)
#define OFF_STATS  (OFF_BIASP + DD)           // NSH rows x 1024: [0:256)=s1 sum, [256:512)=s1 sq, [512:768)=s2 sum, [768:1024)=s2 sq
#define OFF_MAXK   (OFF_STATS + NSH*1024)
#define OFF_MINK   (OFF_MAXK + NPTS*DD)
#define OFF_PMAX   (OFF_MINK + NPTS*DD)
#define OFF_PMIN   (OFF_PMAX + BB*32*DD)
// total ~ 136 MB

__device__ __forceinline__ float block_sum256(float v, float* red, int tid) {
  #pragma unroll
  for (int off = 32; off; off >>= 1) v += __shfl_down(v, off, 64);
  __syncthreads();
  if ((tid & 63) == 0) red[tid >> 6] = v;
  __syncthreads();
  return red[0] + red[1] + red[2] + red[3];
}

// ---------------- per-point features -> feat[16384,768] (each 256-chunk l2-normalized)
__global__ __launch_bounds__(256) void featurize(
    const int* __restrict__ cls, const float* __restrict__ colors, const float* __restrict__ positions,
    const float* __restrict__ ctab,
    const float* __restrict__ pW1, const float* __restrict__ pb1, const float* __restrict__ pW2, const float* __restrict__ pb2,
    const float* __restrict__ cW1, const float* __restrict__ cb1, const float* __restrict__ cW2, const float* __restrict__ cb2,
    float* __restrict__ feat)
{
  __shared__ float colh[32], posh[32];
  __shared__ float red[4];
  int p = blockIdx.x;
  int tid = threadIdx.x;
  float c0 = colors[p*3+0], c1 = colors[p*3+1], c2 = colors[p*3+2];
  float q0 = positions[p*3+0], q1 = positions[p*3+1], q2 = positions[p*3+2];
  if (tid < 32) {
    colh[tid] = fmaxf(c0*cW1[tid] + c1*cW1[32+tid] + c2*cW1[64+tid] + cb1[tid], 0.f);
    posh[tid] = fmaxf(q0*pW1[tid] + q1*pW1[32+tid] + q2*pW1[64+tid] + pb1[tid], 0.f);
  }
  __syncthreads();
  int c = tid;
  float ce = ctab[cls[p]*DD + c];
  float col = cb2[c], pos = pb2[c];
  #pragma unroll
  for (int k = 0; k < 32; k++) {
    col += colh[k]*cW2[k*DD + c];
    pos += posh[k]*pW2[k*DD + c];
  }
  col = fmaxf(col, 0.f); pos = fmaxf(pos, 0.f);
  float sce  = block_sum256(ce*ce,  red, tid);
  float scol = block_sum256(col*col, red, tid);
  float spos = block_sum256(pos*pos, red, tid);
  float* fp = feat + (size_t)p*768;
  fp[c]       = ce  / fmaxf(sqrtf(sce),  1e-12f);
  fp[256 + c] = col / fmaxf(sqrtf(scol), 1e-12f);
  fp[512 + c] = pos / fmaxf(sqrtf(spos), 1e-12f);
}

// ---------------- generic 64x64-tile GEMM: C[M,256] = act(A[M,KD] @ W[KD,256] (+bias))
template<int KD, bool RELU, bool HASBIAS>
__global__ __launch_bounds__(256) void gemm64(
    const float* __restrict__ A, const float* __restrict__ W, const float* __restrict__ bias,
    float* __restrict__ C)
{
  __shared__ float aT[32][68];
  __shared__ float bS[32][68];
  int tid = threadIdx.x;
  int tx = tid & 15, ty = tid >> 4;
  int rowbase = blockIdx.x * 64;
  int colbase = blockIdx.y * 64;
  int sr = tid >> 2, sk = (tid & 3) * 8;
  float acc[4][4] = {};
  for (int kc = 0; kc < KD; kc += 32) {
    const float* ap = A + (size_t)(rowbase + sr)*KD + kc + sk;
    float4 a0 = *(const float4*)ap;
    float4 a1 = *(const float4*)(ap + 4);
    const float* wp = W + (size_t)(kc + ty)*DD + colbase + tx*4;
    float4 b0  = *(const float4*)wp;
    float4 b1v = *(const float4*)(wp + (size_t)16*DD);
    __syncthreads();
    aT[sk+0][sr]=a0.x; aT[sk+1][sr]=a0.y; aT[sk+2][sr]=a0.z; aT[sk+3][sr]=a0.w;
    aT[sk+4][sr]=a1.x; aT[sk+5][sr]=a1.y; aT[sk+6][sr]=a1.z; aT[sk+7][sr]=a1.w;
    *(float4*)&bS[ty][tx*4]      = b0;
    *(float4*)&bS[ty + 16][tx*4] = b1v;
    __syncthreads();
    #pragma unroll
    for (int k = 0; k < 32; k++) {
      float4 av = *(const float4*)&aT[k][ty*4];
      float4 bv = *(const float4*)&bS[k][tx*4];
      float a_[4] = {av.x, av.y, av.z, av.w};
      float b_[4] = {bv.x, bv.y, bv.z, bv.w};
      #pragma unroll
      for (int rr = 0; rr < 4; rr++)
        #pragma unroll
        for (int cc = 0; cc < 4; cc++)
          acc[rr][cc] += a_[rr]*b_[cc];
    }
  }
  #pragma unroll
  for (int rr = 0; rr < 4; rr++) {
    int row = rowbase + ty*4 + rr;
    float o[4];
    #pragma unroll
    for (int cc = 0; cc < 4; cc++) {
      float v = acc[rr][cc];
      if (HASBIAS) v += bias[colbase + tx*4 + cc];
      if (RELU) v = fmaxf(v, 0.f);
      o[cc] = v;
    }
    *(float4*)&C[(size_t)row*DD + colbase + tx*4] = make_float4(o[0],o[1],o[2],o[3]);
  }
}

// ---------------- sum-of-squares per point (one wave per point)
__global__ __launch_bounds__(256) void sqk(const float* __restrict__ x, float* __restrict__ sq) {
  int tid = threadIdx.x;
  int p = blockIdx.x*4 + (tid >> 6);
  int lane = tid & 63;
  float4 v = *(const float4*)&x[(size_t)p*DD + lane*4];
  float s = v.x*v.x + v.y*v.y + v.z*v.z + v.w*v.w;
  #pragma unroll
  for (int off = 32; off; off >>= 1) s += __shfl_down(s, off, 64);
  if (lane == 0) sq[p] = s;
}

// ---------------- Wu = W1_top - W1_bot
__global__ __launch_bounds__(256) void prep_wu(const float* __restrict__ gW1, float* __restrict__ Wu) {
  int i = blockIdx.x*256 + threadIdx.x;
  Wu[i] = gW1[i] - gW1[i + DD*DD];
}

// ---------------- kNN partial: per (batch, 64-row i-tile, j-quarter), keep 8 smallest d
// Software-pipelined: global loads for step c+1 issue before compute of step c.
__global__ __launch_bounds__(256) void knnk(const float* __restrict__ x, const float* __restrict__ sq,
                                            float* __restrict__ pdg, int* __restrict__ pjg)
{
  __shared__ float aT[32][68];
  __shared__ float bT[32][68];
  __shared__ float dt[64][65];
  __shared__ float sqI[64], sqJ[64];
  int tid = threadIdx.x;
  int q  = blockIdx.x & 3;
  int it = (blockIdx.x >> 2) & 31;
  int bb = blockIdx.x >> 7;
  int ibase = it * 64;
  const float* xb  = x  + (size_t)bb*NN*DD;
  const float* sqb = sq + (size_t)bb*NN;
  int tx = tid & 15, ty = tid >> 4;
  int sr = tid >> 2, sk = (tid & 3) * 8;
  int selrow = tid & 63, selseg = tid >> 6;
  float bd[8]; int bj[8];
  #pragma unroll
  for (int s = 0; s < 8; s++) { bd[s] = 3.4e38f; bj[s] = 0; }
  if (tid < 64) sqI[tid] = sqb[ibase + tid];
  // prefetch step 0
  float4 a0, a1, b0, b1; float sjv = 0.f;
  {
    const float* ap = xb + (size_t)(ibase + sr)*DD + sk;
    a0 = *(const float4*)ap; a1 = *(const float4*)(ap + 4);
    const float* bp = xb + (size_t)(q*512 + sr)*DD + sk;
    b0 = *(const float4*)bp; b1 = *(const float4*)(bp + 4);
    if (tid < 64) sjv = sqb[q*512 + tid];
  }
  float acc[4][4] = {};
  #pragma unroll 1
  for (int c = 0; c < 64; c++) {
    __syncthreads();
    aT[sk+0][sr]=a0.x; aT[sk+1][sr]=a0.y; aT[sk+2][sr]=a0.z; aT[sk+3][sr]=a0.w;
    aT[sk+4][sr]=a1.x; aT[sk+5][sr]=a1.y; aT[sk+6][sr]=a1.z; aT[sk+7][sr]=a1.w;
    bT[sk+0][sr]=b0.x; bT[sk+1][sr]=b0.y; bT[sk+2][sr]=b0.z; bT[sk+3][sr]=b0.w;
    bT[sk+4][sr]=b1.x; bT[sk+5][sr]=b1.y; bT[sk+6][sr]=b1.z; bT[sk+7][sr]=b1.w;
    if ((c & 7) == 0 && tid < 64) sqJ[tid] = sjv;
    __syncthreads();
    // prefetch step c+1 (overlaps compute below)
    if (c < 63) {
      int cn = c + 1;
      int jtn = cn >> 3, kcn = (cn & 7) * 32;
      int jbn = q*512 + jtn*64;
      const float* ap = xb + (size_t)(ibase + sr)*DD + kcn + sk;
      a0 = *(const float4*)ap; a1 = *(const float4*)(ap + 4);
      const float* bp = xb + (size_t)(jbn + sr)*DD + kcn + sk;
      b0 = *(const float4*)bp; b1 = *(const float4*)(bp + 4);
      if ((cn & 7) == 0 && tid < 64) sjv = sqb[jbn + tid];
    }
    #pragma unroll
    for (int k = 0; k < 32; k++) {
      float4 av = *(const float4*)&aT[k][ty*4];
      float4 bv = *(const float4*)&bT[k][tx*4];
      float a_[4] = {av.x, av.y, av.z, av.w};
      float b_[4] = {bv.x, bv.y, bv.z, bv.w};
      #pragma unroll
      for (int rr = 0; rr < 4; rr++)
        #pragma unroll
        for (int cc = 0; cc < 4; cc++)
          acc[rr][cc] += a_[rr]*b_[cc];
    }
    if ((c & 7) == 7) {
      int jbase = q*512 + (c >> 3)*64;
      #pragma unroll
      for (int rr = 0; rr < 4; rr++)
        #pragma unroll
        for (int cc = 0; cc < 4; cc++) {
          dt[ty*4+rr][tx*4+cc] = sqI[ty*4+rr] + sqJ[tx*4+cc] - 2.f*acc[rr][cc];
          acc[rr][cc] = 0.f;
        }
      __syncthreads();
      int cb = selseg*16;
      #pragma unroll
      for (int s = 0; s < 16; s++) {
        float dv = dt[selrow][cb + s];
        if (dv < bd[7]) {
          bd[7] = dv; bj[7] = jbase + cb + s;
          #pragma unroll
          for (int t = 7; t >= 1; t--) {
            if (bd[t] < bd[t-1]) {
              float td = bd[t]; bd[t] = bd[t-1]; bd[t-1] = td;
              int   tj = bj[t]; bj[t] = bj[t-1]; bj[t-1] = tj;
            }
          }
        }
      }
    }
  }
  // stage per-thread lists in LDS (overlay aT/bT — GEMM done; dt still live for laggards, disjoint)
  float* pdl = &aT[0][0];
  int*   pjl = (int*)&bT[0][0];
  #pragma unroll
  for (int s = 0; s < 8; s++) {
    pdl[tid*8 + s] = bd[s];
    pjl[tid*8 + s] = bj[s];
  }
  __syncthreads();
  if (tid < 64) {
    float md[8]; int mj[8];
    #pragma unroll
    for (int s = 0; s < 8; s++) { md[s] = 3.4e38f; mj[s] = 0; }
    #pragma unroll 1
    for (int g = 0; g < 4; g++) {
      int base = (g*64 + tid)*8;
      #pragma unroll
      for (int s = 0; s < 8; s++) {
        float dv = pdl[base + s];
        if (dv < md[7]) {
          md[7] = dv; mj[7] = pjl[base + s];
          #pragma unroll
          for (int t = 7; t >= 1; t--) {
            if (md[t] < md[t-1]) {
              float td = md[t]; md[t] = md[t-1]; md[t-1] = td;
              int   tj = mj[t]; mj[t] = mj[t-1]; mj[t-1] = tj;
            }
          }
        }
      }
    }
    size_t gbase = ((size_t)(bb*NN + ibase + tid))*32 + (size_t)q*8;
    #pragma unroll
    for (int s = 0; s < 8; s++) {
      pdg[gbase + s] = md[s];
      pjg[gbase + s] = bb*NN + mj[s];
    }
  }
}

// ---------------- merge 4 quarter-lists per point -> final 8 neighbor indices
__global__ __launch_bounds__(256) void knnmerge(const float* __restrict__ pdg, const int* __restrict__ pjg,
                                                int* __restrict__ idxg)
{
  int p = blockIdx.x*256 + threadIdx.x;
  float md[8]; int mj[8];
  #pragma unroll
  for (int s = 0; s < 8; s++) { md[s] = 3.4e38f; mj[s] = 0; }
  size_t base = (size_t)p*32;
  #pragma unroll 1
  for (int s = 0; s < 32; s++) {
    float dv = pdg[base + s];
    if (dv < md[7]) {
      md[7] = dv; mj[7] = pjg[base + s];
      #pragma unroll
      for (int t = 7; t >= 1; t--) {
        if (md[t] < md[t-1]) {
          float td = md[t]; md[t] = md[t-1]; md[t-1] = td;
          int   tj = mj[t]; mj[t] = mj[t-1]; mj[t-1] = tj;
        }
      }
    }
  }
  #pragma unroll
  for (int s = 0; s < 8; s++) idxg[(size_t)p*8 + s] = mj[s];
}

// ---------------- BN1 stats: h1 = relu(u_i + v_j + b1), coalesced whole-row reads,
// u-row reused across its 8 edges, shadow-accumulator atomics (8 contenders/address)
__global__ __launch_bounds__(256) void bn1stats(const float* __restrict__ u, const float* __restrict__ v,
    const int* __restrict__ idxg, const float* __restrict__ b1, float* __restrict__ stats)
{
  __shared__ int jL[256];
  int c = threadIdx.x;
  int n0 = blockIdx.x * 32;
  jL[c] = idxg[(size_t)n0*8 + c];
  __syncthreads();
  float b1c = b1[c];
  float s = 0.f, s2 = 0.f;
  #pragma unroll 1
  for (int n = 0; n < 32; n++) {
    float uc = u[(size_t)(n0 + n)*DD + c];
    #pragma unroll
    for (int e = 0; e < 8; e++) {
      int j = jL[n*8 + e];
      float h = fmaxf(uc + v[(size_t)j*DD + c] + b1c, 0.f);
      s += h; s2 += h*h;
    }
  }
  int row = blockIdx.x & (NSH - 1);
  atomicAdd(&stats[row*1024 + c], s);
  atomicAdd(&stats[row*1024 + 256 + c], s2);
}

// ---------------- fold BN1 into layer-2 weights: W2' = diag(s1) W2 ; bias' = b2 + t1.W2
__global__ __launch_bounds__(256) void prep2(const float* __restrict__ stats, const float* __restrict__ g1,
    const float* __restrict__ be1, const float* __restrict__ gW2, const float* __restrict__ gb2,
    float* __restrict__ W2p, float* __restrict__ biasp)
{
  __shared__ float s1L[256], t1L[256];
  int tid = threadIdx.x;
  const float inv = 1.f / (float)NEDGE;
  float sm = 0.f, sq2 = 0.f;
  #pragma unroll 1
  for (int r = 0; r < NSH; r++) {
    sm  += stats[r*1024 + tid];
    sq2 += stats[r*1024 + 256 + tid];
  }
  float m = sm * inv;
  float var = sq2*inv - m*m;
  float s1 = g1[tid] / sqrtf(var + BN_EPS);
  s1L[tid] = s1; t1L[tid] = be1[tid] - m*s1;
  __syncthreads();
  float bacc = gb2[tid];
  for (int k = 0; k < DD; k++) {
    float w = gW2[k*DD + tid];
    W2p[k*DD + tid] = s1L[k]*w;
    bacc += t1L[k]*w;
  }
  biasp[tid] = bacc;
}

// ---------------- edge GEMM: h2 = relu( relu(u_i+v_j+b1) @ W2' + bias' )
// Split-B (two 128-col halves), software-pipelined gathers & weight loads,
// per-(node,c) max/min over K, shadow-accumulated BN2 sums.
__global__ __launch_bounds__(256) void edgek(
    const float* __restrict__ u, const float* __restrict__ v, const int* __restrict__ idxg,
    const float* __restrict__ b1, const float* __restrict__ W2p, const float* __restrict__ biasp,
    float* __restrict__ maxK, float* __restrict__ minK, float* __restrict__ stats)
{
  __shared__ float aT[32][68];
  __shared__ float bS[32][132];
  __shared__ int   jL[64];
  __shared__ float b1L[256];
  __shared__ float redS[4][256];
  __shared__ float redQ[4][256];
  int tid = threadIdx.x;
  int tx = tid & 15, ty = tid >> 4;
  int rowbase = blockIdx.x * 64;
  if (tid < 64) jL[tid] = idxg[rowbase + tid];
  b1L[tid] = b1[tid];
  __syncthreads();
  int sr = tid >> 2, sk = (tid & 3) * 8;
  int iu = (rowbase + sr) >> 3;
  int wr = tid >> 5;            // 0..7
  int wc = (tid & 31) * 4;      // 0..124
  int jv = jL[sr];
  const float* urow = u + (size_t)iu*DD;
  const float* vrow = v + (size_t)jv*DD;
  // prefetch chunk-0 A operands and chunk-0 half-0 weights
  float4 u0 = *(const float4*)(urow + sk);
  float4 u1 = *(const float4*)(urow + sk + 4);
  float4 v0 = *(const float4*)(vrow + sk);
  float4 v1 = *(const float4*)(vrow + sk + 4);
  float4 w0 = *(const float4*)&W2p[(size_t)(wr     )*DD + wc];
  float4 w1 = *(const float4*)&W2p[(size_t)(wr +  8)*DD + wc];
  float4 w2 = *(const float4*)&W2p[(size_t)(wr + 16)*DD + wc];
  float4 w3 = *(const float4*)&W2p[(size_t)(wr + 24)*DD + wc];
  float acc[4][16] = {};
  #pragma unroll 1
  for (int kc8 = 0; kc8 < 8; kc8++) {
    int kc = kc8 * 32;
    __syncthreads();
    aT[sk+0][sr] = fmaxf(u0.x+v0.x+b1L[kc+sk+0], 0.f);
    aT[sk+1][sr] = fmaxf(u0.y+v0.y+b1L[kc+sk+1], 0.f);
    aT[sk+2][sr] = fmaxf(u0.z+v0.z+b1L[kc+sk+2], 0.f);
    aT[sk+3][sr] = fmaxf(u0.w+v0.w+b1L[kc+sk+3], 0.f);
    aT[sk+4][sr] = fmaxf(u1.x+v1.x+b1L[kc+sk+4], 0.f);
    aT[sk+5][sr] = fmaxf(u1.y+v1.y+b1L[kc+sk+5], 0.f);
    aT[sk+6][sr] = fmaxf(u1.z+v1.z+b1L[kc+sk+6], 0.f);
    aT[sk+7][sr] = fmaxf(u1.w+v1.w+b1L[kc+sk+7], 0.f);
    *(float4*)&bS[wr     ][wc] = w0;
    *(float4*)&bS[wr +  8][wc] = w1;
    *(float4*)&bS[wr + 16][wc] = w2;
    *(float4*)&bS[wr + 24][wc] = w3;
    __syncthreads();
    // prefetch next chunk's A gathers (longest latency, issued earliest)
    if (kc8 < 7) {
      int kcn = kc + 32;
      u0 = *(const float4*)(urow + kcn + sk);
      u1 = *(const float4*)(urow + kcn + sk + 4);
      v0 = *(const float4*)(vrow + kcn + sk);
      v1 = *(const float4*)(vrow + kcn + sk + 4);
    }
    // prefetch this chunk's half-1 weights
    w0 = *(const float4*)&W2p[(size_t)(kc + wr     )*DD + 128 + wc];
    w1 = *(const float4*)&W2p[(size_t)(kc + wr +  8)*DD + 128 + wc];
    w2 = *(const float4*)&W2p[(size_t)(kc + wr + 16)*DD + 128 + wc];
    w3 = *(const float4*)&W2p[(size_t)(kc + wr + 24)*DD + 128 + wc];
    // compute half 0 (cols 0..127)
    #pragma unroll
    for (int k = 0; k < 32; k++) {
      float4 av = *(const float4*)&aT[k][ty*4];
      float a_[4] = {av.x, av.y, av.z, av.w};
      #pragma unroll
      for (int qq = 0; qq < 2; qq++) {
        float4 bv = *(const float4*)&bS[k][qq*64 + tx*4];
        float b_[4] = {bv.x, bv.y, bv.z, bv.w};
        #pragma unroll
        for (int rr = 0; rr < 4; rr++)
          #pragma unroll
          for (int cc = 0; cc < 4; cc++)
            acc[rr][qq*4+cc] += a_[rr]*b_[cc];
      }
    }
    __syncthreads();
    *(float4*)&bS[wr     ][wc] = w0;
    *(float4*)&bS[wr +  8][wc] = w1;
    *(float4*)&bS[wr + 16][wc] = w2;
    *(float4*)&bS[wr + 24][wc] = w3;
    __syncthreads();
    // prefetch next chunk's half-0 weights
    if (kc8 < 7) {
      int kcn = kc + 32;
      w0 = *(const float4*)&W2p[(size_t)(kcn + wr     )*DD + wc];
      w1 = *(const float4*)&W2p[(size_t)(kcn + wr +  8)*DD + wc];
      w2 = *(const float4*)&W2p[(size_t)(kcn + wr + 16)*DD + wc];
      w3 = *(const float4*)&W2p[(size_t)(kcn + wr + 24)*DD + wc];
    }
    // compute half 1 (cols 128..255)
    #pragma unroll
    for (int k = 0; k < 32; k++) {
      float4 av = *(const float4*)&aT[k][ty*4];
      float a_[4] = {av.x, av.y, av.z, av.w};
      #pragma unroll
      for (int qq = 0; qq < 2; qq++) {
        float4 bv = *(const float4*)&bS[k][qq*64 + tx*4];
        float b_[4] = {bv.x, bv.y, bv.z, bv.w};
        #pragma unroll
        for (int rr = 0; rr < 4; rr++)
          #pragma unroll
          for (int cc = 0; cc < 4; cc++)
            acc[rr][8 + qq*4+cc] += a_[rr]*b_[cc];
      }
    }
  }
  // epilogue: bias + relu, per-node (8 rows) max/min, block stats
  float mx[16], mn[16], sS[16], sQ[16];
  #pragma unroll
  for (int q4 = 0; q4 < 4; q4++) {
    #pragma unroll
    for (int cc = 0; cc < 4; cc++) {
      int col = q4*64 + tx*4 + cc;
      float bp = biasp[col];
      int qi = q4*4 + cc;
      float h0 = fmaxf(acc[0][qi] + bp, 0.f);
      float h1 = fmaxf(acc[1][qi] + bp, 0.f);
      float h2 = fmaxf(acc[2][qi] + bp, 0.f);
      float h3 = fmaxf(acc[3][qi] + bp, 0.f);
      mx[qi] = fmaxf(fmaxf(h0,h1), fmaxf(h2,h3));
      mn[qi] = fminf(fminf(h0,h1), fminf(h2,h3));
      sS[qi] = h0+h1+h2+h3;
      sQ[qi] = h0*h0+h1*h1+h2*h2+h3*h3;
    }
  }
  #pragma unroll
  for (int qi = 0; qi < 16; qi++) {
    mx[qi] = fmaxf(mx[qi], __shfl_xor(mx[qi], 16, 64));
    mn[qi] = fminf(mn[qi], __shfl_xor(mn[qi], 16, 64));
  }
  if ((ty & 1) == 0) {
    int node = (rowbase >> 3) + (ty >> 1);
    #pragma unroll
    for (int q4 = 0; q4 < 4; q4++) {
      *(float4*)&maxK[(size_t)node*DD + q4*64 + tx*4] =
          make_float4(mx[q4*4+0], mx[q4*4+1], mx[q4*4+2], mx[q4*4+3]);
      *(float4*)&minK[(size_t)node*DD + q4*64 + tx*4] =
          make_float4(mn[q4*4+0], mn[q4*4+1], mn[q4*4+2], mn[q4*4+3]);
    }
  }
  #pragma unroll
  for (int qi = 0; qi < 16; qi++) {
    sS[qi] += __shfl_xor(sS[qi], 16, 64);
    sS[qi] += __shfl_xor(sS[qi], 32, 64);
    sQ[qi] += __shfl_xor(sQ[qi], 16, 64);
    sQ[qi] += __shfl_xor(sQ[qi], 32, 64);
  }
  int w = tid >> 6;
  if ((tid & 63) < 16) {
    #pragma unroll
    for (int q4 = 0; q4 < 4; q4++)
      #pragma unroll
      for (int cc = 0; cc < 4; cc++) {
        redS[w][q4*64 + tx*4 + cc] = sS[q4*4+cc];
        redQ[w][q4*64 + tx*4 + cc] = sQ[q4*4+cc];
      }
  }
  __syncthreads();
  float ts = redS[0][tid]+redS[1][tid]+redS[2][tid]+redS[3][tid];
  float tq = redQ[0][tid]+redQ[1][tid]+redQ[2][tid]+redQ[3][tid];
  int row = blockIdx.x & (NSH - 1);
  atomicAdd(&stats[row*1024 + 512 + tid], ts);
  atomicAdd(&stats[row*1024 + 768 + tid], tq);
}

// ---------------- partial max/min over n (64 rows per block)
__global__ __launch_bounds__(256) void poolpart(const float* __restrict__ maxK, const float* __restrict__ minK,
    float* __restrict__ pmax, float* __restrict__ pmin)
{
  int b = blockIdx.x, ns = blockIdx.y, c = threadIdx.x;
  float mx = -3.4e38f, mn = 3.4e38f;
  size_t base = ((size_t)b*NN + ns*64)*DD + c;
  for (int n = 0; n < 64; n++) {
    mx = fmaxf(mx, maxK[base + (size_t)n*DD]);
    mn = fminf(mn, minK[base + (size_t)n*DD]);
  }
  pmax[((size_t)b*32 + ns)*DD + c] = mx;
  pmin[((size_t)b*32 + ns)*DD + c] = mn;
}

// ---------------- final: BN2 on pooled max/min, two 256x256 linears, l2norm
__global__ __launch_bounds__(256) void finalk(const float* __restrict__ pmax, const float* __restrict__ pmin,
    const float* __restrict__ stats, const float* __restrict__ g2, const float* __restrict__ be2,
    const float* __restrict__ W1, const float* __restrict__ b1,
    const float* __restrict__ W2, const float* __restrict__ b2,
    float* __restrict__ out)
{
  __shared__ float pl[8][256];
  __shared__ float hl[8][256];
  __shared__ float nrm[8];
  int c = threadIdx.x;
  const float inv = 1.f / (float)NEDGE;
  float sm = 0.f, sq2 = 0.f;
  #pragma unroll 1
  for (int r = 0; r < NSH; r++) {
    sm  += stats[r*1024 + 512 + c];
    sq2 += stats[r*1024 + 768 + c];
  }
  float m = sm * inv;
  float var = sq2*inv - m*m;
  float s2 = g2[c] / sqrtf(var + BN_EPS);
  float t2 = be2[c] - m*s2;
  #pragma unroll
  for (int b = 0; b < 8; b++) {
    float mx = -3.4e38f, mn = 3.4e38f;
    for (int ns = 0; ns < 32; ns++) {
      mx = fmaxf(mx, pmax[((size_t)b*32+ns)*DD + c]);
      mn = fminf(mn, pmin[((size_t)b*32+ns)*DD + c]);
    }
    pl[b][c] = (s2 >= 0.f) ? s2*mx + t2 : s2*mn + t2;
  }
  __syncthreads();
  float h[8];
  #pragma unroll
  for (int b = 0; b < 8; b++) h[b] = b1[c];
  for (int k = 0; k < 256; k++) {
    float w = W1[k*256 + c];
    #pragma unroll
    for (int b = 0; b < 8; b++) h[b] += pl[b][k]*w;
  }
  __syncthreads();
  #pragma unroll
  for (int b = 0; b < 8; b++) hl[b][c] = fmaxf(h[b], 0.f);
  __syncthreads();
  float o[8];
  #pragma unroll
  for (int b = 0; b < 8; b++) o[b] = b2[c];
  for (int k = 0; k < 256; k++) {
    float w = W2[k*256 + c];
    #pragma unroll
    for (int b = 0; b < 8; b++) o[b] += hl[b][k]*w;
  }
  __syncthreads();
  #pragma unroll
  for (int b = 0; b < 8; b++) pl[b][c] = fmaxf(o[b], 0.f);
  __syncthreads();
  if (c < 8) {
    float s = 0.f;
    for (int k = 0; k < 256; k++) { float vv = pl[c][k]; s += vv*vv; }
    nrm[c] = fmaxf(sqrtf(s), 1e-12f);
  }
  __syncthreads();
  #pragma unroll
  for (int b = 0; b < 8; b++) out[b*256 + c] = pl[b][c] / nrm[b];
}

extern "C" void kernel_launch(void* const* d_in, const int* in_sizes, int n_in,
                              void* d_out, int out_size, void* d_ws, size_t ws_size,
                              hipStream_t stream) {
  (void)in_sizes; (void)n_in; (void)out_size; (void)ws_size;
  const int*   cls       = (const int*)  d_in[0];
  const float* colors    = (const float*)d_in[1];
  const float* positions = (const float*)d_in[2];
  const float* ctab      = (const float*)d_in[3];
  const float* pW1 = (const float*)d_in[4];
  const float* pb1 = (const float*)d_in[5];
  const float* pW2 = (const float*)d_in[6];
  const float* pb2 = (const float*)d_in[7];
  const float* cW1 = (const float*)d_in[8];
  const float* cb1 = (const float*)d_in[9];
  const float* cW2 = (const float*)d_in[10];
  const float* cb2 = (const float*)d_in[11];
  const float* mW  = (const float*)d_in[12];
  const float* mb  = (const float*)d_in[13];
  const float* gW1 = (const float*)d_in[14];
  const float* gb1 = (const float*)d_in[15];
  const float* gg1 = (const float*)d_in[16];
  const float* gbe1= (const float*)d_in[17];
  const float* gW2 = (const float*)d_in[18];
  const float* gb2 = (const float*)d_in[19];
  const float* gg2 = (const float*)d_in[20];
  const float* gbe2= (const float*)d_in[21];
  const float* lW1 = (const float*)d_in[22];
  const float* lb1 = (const float*)d_in[23];
  const float* lW2 = (const float*)d_in[24];
  const float* lb2 = (const float*)d_in[25];
  float* out = (float*)d_out;

  float* wsf   = (float*)d_ws;
  float* x     = wsf + OFF_X;
  float* feat  = wsf + OFF_FEAT;
  float* sq    = wsf + OFF_SQ;
  int*   idxg  = (int*)(wsf + OFF_IDX);
  float* u     = wsf + OFF_U;
  float* v     = wsf + OFF_V;
  float* Wu    = wsf + OFF_WU;
  float* W2p   = wsf + OFF_W2P;
  float* biasp = wsf + OFF_BIASP;
  float* stats = wsf + OFF_STATS;
  float* maxK  = wsf + OFF_MAXK;
  float* minK  = wsf + OFF_MINK;
  float* pmax  = wsf + OFF_PMAX;
  float* pmin  = wsf + OFF_PMIN;
  // partial kNN buffers overlay feat (dead after the merge GEMM)
  float* pdg   = feat;
  int*   pjg   = (int*)(feat + (size_t)NPTS*32);

  hipMemsetAsync(stats, 0, NSH*1024*sizeof(float), stream);

  featurize<<<NPTS, 256, 0, stream>>>(cls, colors, positions, ctab,
                                      pW1, pb1, pW2, pb2, cW1, cb1, cW2, cb2, feat);
  gemm64<768, true, true><<<dim3(NPTS/64, 4), 256, 0, stream>>>(feat, mW, mb, x);
  sqk<<<NPTS/4, 256, 0, stream>>>(x, sq);
  prep_wu<<<DD*DD/256, 256, 0, stream>>>(gW1, Wu);
  knnk<<<BB*32*4, 256, 0, stream>>>(x, sq, pdg, pjg);
  knnmerge<<<NPTS/256, 256, 0, stream>>>(pdg, pjg, idxg);
  gemm64<256, false, false><<<dim3(NPTS/64, 4), 256, 0, stream>>>(x, Wu, nullptr, u);
  gemm64<256, false, false><<<dim3(NPTS/64, 4), 256, 0, stream>>>(x, gW1 + DD*DD, nullptr, v);
  bn1stats<<<NPTS/32, 256, 0, stream>>>(u, v, idxg, gb1, stats);
  prep2<<<1, 256, 0, stream>>>(stats, gg1, gbe1, gW2, gb2, W2p, biasp);
  edgek<<<NEDGE/64, 256, 0, stream>>>(u, v, idxg, gb1, W2p, biasp, maxK, minK, stats);
  poolpart<<<dim3(BB, 32), 256, 0, stream>>>(maxK, minK, pmax, pmin);
  finalk<<<1, 256, 0, stream>>>(pmax, pmin, stats, gg2, gbe2, lW1, lb1, lW2, lb2, out);
}

// Round 4
// 954.004 us; speedup vs baseline: 1.1649x; 1.1649x over previous
//
#include <hip/hip_runtime.h>
#include <math.h>

#define BB 8
#define NN 2048
#define DD 256
#define KNN 8
#define NPTS (BB*NN)        // 16384
#define NEDGE (NPTS*KNN)    // 131072
#define BN_EPS 1e-5f
#define NSH 64              // shadow copies for stats accumulation (atomic decontention)

// ---- workspace layout (float offsets) ----
#define OFF_X      0
#define OFF_FEAT   (OFF_X + NPTS*DD)
#define OFF_SQ     (OFF_FEAT + NPTS*3*DD)
#define OFF_IDX    (OFF_SQ + NPTS)
#define OFF_U      (OFF_IDX + NEDGE)
#define OFF_V      (OFF_U + NPTS*DD)
#define OFF_WU     (OFF_V + NPTS*DD)
#define OFF_W2P    (OFF_WU + DD*DD)
#define OFF_BIASP  (OFF_W2P + DD*DD)
#define OFF_STATS  (OFF_BIASP + DD)           // NSH rows x 1024: [0:256)=s1 sum, [256:512)=s1 sq, [512:768)=s2 sum, [768:1024)=s2 sq
#define OFF_MAXK   (OFF_STATS + NSH*1024)
#define OFF_MINK   (OFF_MAXK + NPTS*DD)
#define OFF_PMAX   (OFF_MINK + NPTS*DD)
#define OFF_PMIN   (OFF_PMAX + BB*32*DD)

__device__ __forceinline__ float block_sum256(float v, float* red, int tid) {
  #pragma unroll
  for (int off = 32; off; off >>= 1) v += __shfl_down(v, off, 64);
  __syncthreads();
  if ((tid & 63) == 0) red[tid >> 6] = v;
  __syncthreads();
  return red[0] + red[1] + red[2] + red[3];
}

// ---------------- per-point features -> feat[16384,768] (each 256-chunk l2-normalized)
__global__ __launch_bounds__(256) void featurize(
    const int* __restrict__ cls, const float* __restrict__ colors, const float* __restrict__ positions,
    const float* __restrict__ ctab,
    const float* __restrict__ pW1, const float* __restrict__ pb1, const float* __restrict__ pW2, const float* __restrict__ pb2,
    const float* __restrict__ cW1, const float* __restrict__ cb1, const float* __restrict__ cW2, const float* __restrict__ cb2,
    float* __restrict__ feat)
{
  __shared__ float colh[32], posh[32];
  __shared__ float red[4];
  int p = blockIdx.x;
  int tid = threadIdx.x;
  float c0 = colors[p*3+0], c1 = colors[p*3+1], c2 = colors[p*3+2];
  float q0 = positions[p*3+0], q1 = positions[p*3+1], q2 = positions[p*3+2];
  if (tid < 32) {
    colh[tid] = fmaxf(c0*cW1[tid] + c1*cW1[32+tid] + c2*cW1[64+tid] + cb1[tid], 0.f);
    posh[tid] = fmaxf(q0*pW1[tid] + q1*pW1[32+tid] + q2*pW1[64+tid] + pb1[tid], 0.f);
  }
  __syncthreads();
  int c = tid;
  float ce = ctab[cls[p]*DD + c];
  float col = cb2[c], pos = pb2[c];
  #pragma unroll
  for (int k = 0; k < 32; k++) {
    col += colh[k]*cW2[k*DD + c];
    pos += posh[k]*pW2[k*DD + c];
  }
  col = fmaxf(col, 0.f); pos = fmaxf(pos, 0.f);
  float sce  = block_sum256(ce*ce,  red, tid);
  float scol = block_sum256(col*col, red, tid);
  float spos = block_sum256(pos*pos, red, tid);
  float* fp = feat + (size_t)p*768;
  fp[c]       = ce  / fmaxf(sqrtf(sce),  1e-12f);
  fp[256 + c] = col / fmaxf(sqrtf(scol), 1e-12f);
  fp[512 + c] = pos / fmaxf(sqrtf(spos), 1e-12f);
}

// ---------------- generic 64x64-tile GEMM: C[M,256] = act(A[M,KD] @ W[KD,256] (+bias))
template<int KD, bool RELU, bool HASBIAS>
__global__ __launch_bounds__(256) void gemm64(
    const float* __restrict__ A, const float* __restrict__ W, const float* __restrict__ bias,
    float* __restrict__ C)
{
  __shared__ float aT[32][68];
  __shared__ float bS[32][68];
  int tid = threadIdx.x;
  int tx = tid & 15, ty = tid >> 4;
  int rowbase = blockIdx.x * 64;
  int colbase = blockIdx.y * 64;
  int sr = tid >> 2, sk = (tid & 3) * 8;
  float acc[4][4] = {};
  for (int kc = 0; kc < KD; kc += 32) {
    const float* ap = A + (size_t)(rowbase + sr)*KD + kc + sk;
    float4 a0 = *(const float4*)ap;
    float4 a1 = *(const float4*)(ap + 4);
    const float* wp = W + (size_t)(kc + ty)*DD + colbase + tx*4;
    float4 b0  = *(const float4*)wp;
    float4 b1v = *(const float4*)(wp + (size_t)16*DD);
    __syncthreads();
    aT[sk+0][sr]=a0.x; aT[sk+1][sr]=a0.y; aT[sk+2][sr]=a0.z; aT[sk+3][sr]=a0.w;
    aT[sk+4][sr]=a1.x; aT[sk+5][sr]=a1.y; aT[sk+6][sr]=a1.z; aT[sk+7][sr]=a1.w;
    *(float4*)&bS[ty][tx*4]      = b0;
    *(float4*)&bS[ty + 16][tx*4] = b1v;
    __syncthreads();
    #pragma unroll
    for (int k = 0; k < 32; k++) {
      float4 av = *(const float4*)&aT[k][ty*4];
      float4 bv = *(const float4*)&bS[k][tx*4];
      float a_[4] = {av.x, av.y, av.z, av.w};
      float b_[4] = {bv.x, bv.y, bv.z, bv.w};
      #pragma unroll
      for (int rr = 0; rr < 4; rr++)
        #pragma unroll
        for (int cc = 0; cc < 4; cc++)
          acc[rr][cc] += a_[rr]*b_[cc];
    }
  }
  #pragma unroll
  for (int rr = 0; rr < 4; rr++) {
    int row = rowbase + ty*4 + rr;
    float o[4];
    #pragma unroll
    for (int cc = 0; cc < 4; cc++) {
      float v = acc[rr][cc];
      if (HASBIAS) v += bias[colbase + tx*4 + cc];
      if (RELU) v = fmaxf(v, 0.f);
      o[cc] = v;
    }
    *(float4*)&C[(size_t)row*DD + colbase + tx*4] = make_float4(o[0],o[1],o[2],o[3]);
  }
}

// ---------------- sum-of-squares per point (one wave per point)
__global__ __launch_bounds__(256) void sqk(const float* __restrict__ x, float* __restrict__ sq) {
  int tid = threadIdx.x;
  int p = blockIdx.x*4 + (tid >> 6);
  int lane = tid & 63;
  float4 v = *(const float4*)&x[(size_t)p*DD + lane*4];
  float s = v.x*v.x + v.y*v.y + v.z*v.z + v.w*v.w;
  #pragma unroll
  for (int off = 32; off; off >>= 1) s += __shfl_down(s, off, 64);
  if (lane == 0) sq[p] = s;
}

// ---------------- Wu = W1_top - W1_bot
__global__ __launch_bounds__(256) void prep_wu(const float* __restrict__ gW1, float* __restrict__ Wu) {
  int i = blockIdx.x*256 + threadIdx.x;
  Wu[i] = gW1[i] - gW1[i + DD*DD];
}

// ---------------- kNN partial: per (batch, 64-row i-tile, j-quarter), keep 8 smallest d
// (R2-proven structure: 8 j-tiles x 8 k-chunks, selection across all 256 threads)
__global__ __launch_bounds__(256) void knnk(const float* __restrict__ x, const float* __restrict__ sq,
                                            float* __restrict__ pdg, int* __restrict__ pjg)
{
  __shared__ float aT[32][68];
  __shared__ float bT[32][68];
  __shared__ float dt[64][65];
  __shared__ float sqI[64], sqJ[64];
  int tid = threadIdx.x;
  int q  = blockIdx.x & 3;
  int it = (blockIdx.x >> 2) & 31;
  int bb = blockIdx.x >> 7;
  int ibase = it * 64;
  const float* xb  = x  + (size_t)bb*NN*DD;
  const float* sqb = sq + (size_t)bb*NN;
  int tx = tid & 15, ty = tid >> 4;
  int sr = tid >> 2, sk = (tid & 3) * 8;
  int selrow = tid & 63, selseg = tid >> 6;
  float bd[8]; int bj[8];
  #pragma unroll
  for (int s = 0; s < 8; s++) { bd[s] = 3.4e38f; bj[s] = 0; }
  if (tid < 64) sqI[tid] = sqb[ibase + tid];
  for (int jt = 0; jt < 8; jt++) {
    int jbase = q*512 + jt*64;
    float acc[4][4] = {};
    for (int kc = 0; kc < DD; kc += 32) {
      const float* ap = xb + (size_t)(ibase + sr)*DD + kc + sk;
      float4 a0 = *(const float4*)ap;
      float4 a1 = *(const float4*)(ap + 4);
      const float* bp = xb + (size_t)(jbase + sr)*DD + kc + sk;
      float4 b0  = *(const float4*)bp;
      float4 b1v = *(const float4*)(bp + 4);
      float sjv = 0.f;
      if (kc == 0 && tid < 64) sjv = sqb[jbase + tid];
      __syncthreads();
      aT[sk+0][sr]=a0.x; aT[sk+1][sr]=a0.y; aT[sk+2][sr]=a0.z; aT[sk+3][sr]=a0.w;
      aT[sk+4][sr]=a1.x; aT[sk+5][sr]=a1.y; aT[sk+6][sr]=a1.z; aT[sk+7][sr]=a1.w;
      bT[sk+0][sr]=b0.x; bT[sk+1][sr]=b0.y; bT[sk+2][sr]=b0.z; bT[sk+3][sr]=b0.w;
      bT[sk+4][sr]=b1v.x; bT[sk+5][sr]=b1v.y; bT[sk+6][sr]=b1v.z; bT[sk+7][sr]=b1v.w;
      if (kc == 0 && tid < 64) sqJ[tid] = sjv;
      __syncthreads();
      #pragma unroll
      for (int k = 0; k < 32; k++) {
        float4 av = *(const float4*)&aT[k][ty*4];
        float4 bv = *(const float4*)&bT[k][tx*4];
        float a_[4] = {av.x, av.y, av.z, av.w};
        float b_[4] = {bv.x, bv.y, bv.z, bv.w};
        #pragma unroll
        for (int rr = 0; rr < 4; rr++)
          #pragma unroll
          for (int cc = 0; cc < 4; cc++)
            acc[rr][cc] += a_[rr]*b_[cc];
      }
    }
    #pragma unroll
    for (int rr = 0; rr < 4; rr++)
      #pragma unroll
      for (int cc = 0; cc < 4; cc++)
        dt[ty*4+rr][tx*4+cc] = sqI[ty*4+rr] + sqJ[tx*4+cc] - 2.f*acc[rr][cc];
    __syncthreads();
    int cb = selseg*16;
    #pragma unroll
    for (int s = 0; s < 16; s++) {
      float dv = dt[selrow][cb + s];
      if (dv < bd[7]) {
        bd[7] = dv; bj[7] = jbase + cb + s;
        #pragma unroll
        for (int t = 7; t >= 1; t--) {
          if (bd[t] < bd[t-1]) {
            float td = bd[t]; bd[t] = bd[t-1]; bd[t-1] = td;
            int   tj = bj[t]; bj[t] = bj[t-1]; bj[t-1] = tj;
          }
        }
      }
    }
    __syncthreads();
  }
  // stage per-thread lists in LDS (overlay aT/bT — GEMM done)
  float* pdl = &aT[0][0];
  int*   pjl = (int*)&bT[0][0];
  #pragma unroll
  for (int s = 0; s < 8; s++) {
    pdl[tid*8 + s] = bd[s];
    pjl[tid*8 + s] = bj[s];
  }
  __syncthreads();
  if (tid < 64) {
    float md[8]; int mj[8];
    #pragma unroll
    for (int s = 0; s < 8; s++) { md[s] = 3.4e38f; mj[s] = 0; }
    #pragma unroll 1
    for (int g = 0; g < 4; g++) {
      int base = (g*64 + tid)*8;
      #pragma unroll
      for (int s = 0; s < 8; s++) {
        float dv = pdl[base + s];
        if (dv < md[7]) {
          md[7] = dv; mj[7] = pjl[base + s];
          #pragma unroll
          for (int t = 7; t >= 1; t--) {
            if (md[t] < md[t-1]) {
              float td = md[t]; md[t] = md[t-1]; md[t-1] = td;
              int   tj = mj[t]; mj[t] = mj[t-1]; mj[t-1] = tj;
            }
          }
        }
      }
    }
    size_t gbase = ((size_t)(bb*NN + ibase + tid))*32 + (size_t)q*8;
    #pragma unroll
    for (int s = 0; s < 8; s++) {
      pdg[gbase + s] = md[s];
      pjg[gbase + s] = bb*NN + mj[s];
    }
  }
}

// ---------------- merge 4 quarter-lists per point -> final 8 neighbor indices
__global__ __launch_bounds__(256) void knnmerge(const float* __restrict__ pdg, const int* __restrict__ pjg,
                                                int* __restrict__ idxg)
{
  int p = blockIdx.x*256 + threadIdx.x;
  float md[8]; int mj[8];
  #pragma unroll
  for (int s = 0; s < 8; s++) { md[s] = 3.4e38f; mj[s] = 0; }
  size_t base = (size_t)p*32;
  #pragma unroll 1
  for (int s = 0; s < 32; s++) {
    float dv = pdg[base + s];
    if (dv < md[7]) {
      md[7] = dv; mj[7] = pjg[base + s];
      #pragma unroll
      for (int t = 7; t >= 1; t--) {
        if (md[t] < md[t-1]) {
          float td = md[t]; md[t] = md[t-1]; md[t-1] = td;
          int   tj = mj[t]; mj[t] = mj[t-1]; mj[t-1] = tj;
        }
      }
    }
  }
  #pragma unroll
  for (int s = 0; s < 8; s++) idxg[(size_t)p*8 + s] = mj[s];
}

// ---------------- BN1 stats: h1 = relu(u_i + v_j + b1), coalesced whole-row reads,
// u-row reused across its 8 edges, shadow-accumulator atomics (8 contenders/address)
__global__ __launch_bounds__(256) void bn1stats(const float* __restrict__ u, const float* __restrict__ v,
    const int* __restrict__ idxg, const float* __restrict__ b1, float* __restrict__ stats)
{
  __shared__ int jL[256];
  int c = threadIdx.x;
  int n0 = blockIdx.x * 32;
  jL[c] = idxg[(size_t)n0*8 + c];
  __syncthreads();
  float b1c = b1[c];
  float s = 0.f, s2 = 0.f;
  #pragma unroll 1
  for (int n = 0; n < 32; n++) {
    float uc = u[(size_t)(n0 + n)*DD + c];
    #pragma unroll
    for (int e = 0; e < 8; e++) {
      int j = jL[n*8 + e];
      float h = fmaxf(uc + v[(size_t)j*DD + c] + b1c, 0.f);
      s += h; s2 += h*h;
    }
  }
  int row = blockIdx.x & (NSH - 1);
  atomicAdd(&stats[row*1024 + c], s);
  atomicAdd(&stats[row*1024 + 256 + c], s2);
}

// ---------------- fold BN1 into layer-2 weights: W2' = diag(s1) W2 ; bias' = b2 + t1.W2
__global__ __launch_bounds__(256) void prep2(const float* __restrict__ stats, const float* __restrict__ g1,
    const float* __restrict__ be1, const float* __restrict__ gW2, const float* __restrict__ gb2,
    float* __restrict__ W2p, float* __restrict__ biasp)
{
  __shared__ float s1L[256], t1L[256];
  int tid = threadIdx.x;
  const float inv = 1.f / (float)NEDGE;
  float sm = 0.f, sq2 = 0.f;
  #pragma unroll 1
  for (int r = 0; r < NSH; r++) {
    sm  += stats[r*1024 + tid];
    sq2 += stats[r*1024 + 256 + tid];
  }
  float m = sm * inv;
  float var = sq2*inv - m*m;
  float s1 = g1[tid] / sqrtf(var + BN_EPS);
  s1L[tid] = s1; t1L[tid] = be1[tid] - m*s1;
  __syncthreads();
  float bacc = gb2[tid];
  for (int k = 0; k < DD; k++) {
    float w = gW2[k*DD + tid];
    W2p[k*DD + tid] = s1L[k]*w;
    bacc += t1L[k]*w;
  }
  biasp[tid] = bacc;
}

// ---------------- edge GEMM: h2 = relu( relu(u_i+v_j+b1) @ W2' + bias' )
// R2-proven GEMM structure (full-width B stage, 2 barriers/chunk, low VGPR)
// + shadow-row atomics for BN2 stats.
__global__ __launch_bounds__(256) void edgek(
    const float* __restrict__ u, const float* __restrict__ v, const int* __restrict__ idxg,
    const float* __restrict__ b1, const float* __restrict__ W2p, const float* __restrict__ biasp,
    float* __restrict__ maxK, float* __restrict__ minK, float* __restrict__ stats)
{
  __shared__ float aT[32][68];
  __shared__ float bS[32][260];
  __shared__ int   jL[64];
  __shared__ float redS[4][256];
  __shared__ float redQ[4][256];
  int tid = threadIdx.x;
  int tx = tid & 15, ty = tid >> 4;
  int rowbase = blockIdx.x * 64;
  if (tid < 64) jL[tid] = idxg[rowbase + tid];
  __syncthreads();
  int sr = tid >> 2, sk = (tid & 3) * 8;
  int iu = (rowbase + sr) >> 3;
  int bk = tid >> 6;            // 0..3
  int bc = (tid & 63) * 4;
  float acc[4][16] = {};
  for (int kc = 0; kc < DD; kc += 32) {
    int jv = jL[sr];
    const float* uq = u + (size_t)iu*DD + kc + sk;
    float4 u0 = *(const float4*)uq;
    float4 u1 = *(const float4*)(uq + 4);
    const float* vq = v + (size_t)jv*DD + kc + sk;
    float4 v0 = *(const float4*)vq;
    float4 v1 = *(const float4*)(vq + 4);
    float4 c0 = *(const float4*)&b1[kc + sk];
    float4 c1 = *(const float4*)&b1[kc + sk + 4];
    float4 wreg[8];
    #pragma unroll
    for (int kk = 0; kk < 8; kk++)
      wreg[kk] = *(const float4*)&W2p[(size_t)(kc + bk + kk*4)*DD + bc];
    __syncthreads();
    aT[sk+0][sr] = fmaxf(u0.x+v0.x+c0.x, 0.f);
    aT[sk+1][sr] = fmaxf(u0.y+v0.y+c0.y, 0.f);
    aT[sk+2][sr] = fmaxf(u0.z+v0.z+c0.z, 0.f);
    aT[sk+3][sr] = fmaxf(u0.w+v0.w+c0.w, 0.f);
    aT[sk+4][sr] = fmaxf(u1.x+v1.x+c1.x, 0.f);
    aT[sk+5][sr] = fmaxf(u1.y+v1.y+c1.y, 0.f);
    aT[sk+6][sr] = fmaxf(u1.z+v1.z+c1.z, 0.f);
    aT[sk+7][sr] = fmaxf(u1.w+v1.w+c1.w, 0.f);
    #pragma unroll
    for (int kk = 0; kk < 8; kk++)
      *(float4*)&bS[bk + kk*4][bc] = wreg[kk];
    __syncthreads();
    #pragma unroll
    for (int k = 0; k < 32; k++) {
      float4 av = *(const float4*)&aT[k][ty*4];
      float a_[4] = {av.x, av.y, av.z, av.w};
      #pragma unroll
      for (int q = 0; q < 4; q++) {
        float4 bv = *(const float4*)&bS[k][q*64 + tx*4];
        float b_[4] = {bv.x, bv.y, bv.z, bv.w};
        #pragma unroll
        for (int rr = 0; rr < 4; rr++)
          #pragma unroll
          for (int cc = 0; cc < 4; cc++)
            acc[rr][q*4+cc] += a_[rr]*b_[cc];
      }
    }
  }
  // epilogue: bias + relu, per-node (8 rows) max/min, block stats
  float mx[16], mn[16], sS[16], sQ[16];
  #pragma unroll
  for (int q4 = 0; q4 < 4; q4++) {
    #pragma unroll
    for (int cc = 0; cc < 4; cc++) {
      int col = q4*64 + tx*4 + cc;
      float bp = biasp[col];
      int q = q4*4 + cc;
      float h0 = fmaxf(acc[0][q] + bp, 0.f);
      float h1 = fmaxf(acc[1][q] + bp, 0.f);
      float h2 = fmaxf(acc[2][q] + bp, 0.f);
      float h3 = fmaxf(acc[3][q] + bp, 0.f);
      mx[q] = fmaxf(fmaxf(h0,h1), fmaxf(h2,h3));
      mn[q] = fminf(fminf(h0,h1), fminf(h2,h3));
      sS[q] = h0+h1+h2+h3;
      sQ[q] = h0*h0+h1*h1+h2*h2+h3*h3;
    }
  }
  #pragma unroll
  for (int q = 0; q < 16; q++) {
    mx[q] = fmaxf(mx[q], __shfl_xor(mx[q], 16, 64));
    mn[q] = fminf(mn[q], __shfl_xor(mn[q], 16, 64));
  }
  if ((ty & 1) == 0) {
    int node = (rowbase >> 3) + (ty >> 1);
    #pragma unroll
    for (int q4 = 0; q4 < 4; q4++) {
      *(float4*)&maxK[(size_t)node*DD + q4*64 + tx*4] =
          make_float4(mx[q4*4+0], mx[q4*4+1], mx[q4*4+2], mx[q4*4+3]);
      *(float4*)&minK[(size_t)node*DD + q4*64 + tx*4] =
          make_float4(mn[q4*4+0], mn[q4*4+1], mn[q4*4+2], mn[q4*4+3]);
    }
  }
  #pragma unroll
  for (int q = 0; q < 16; q++) {
    sS[q] += __shfl_xor(sS[q], 16, 64);
    sS[q] += __shfl_xor(sS[q], 32, 64);
    sQ[q] += __shfl_xor(sQ[q], 16, 64);
    sQ[q] += __shfl_xor(sQ[q], 32, 64);
  }
  int w = tid >> 6;
  if ((tid & 63) < 16) {
    #pragma unroll
    for (int q4 = 0; q4 < 4; q4++)
      #pragma unroll
      for (int cc = 0; cc < 4; cc++) {
        redS[w][q4*64 + tx*4 + cc] = sS[q4*4+cc];
        redQ[w][q4*64 + tx*4 + cc] = sQ[q4*4+cc];
      }
  }
  __syncthreads();
  float ts = redS[0][tid]+redS[1][tid]+redS[2][tid]+redS[3][tid];
  float tq = redQ[0][tid]+redQ[1][tid]+redQ[2][tid]+redQ[3][tid];
  int row = blockIdx.x & (NSH - 1);
  atomicAdd(&stats[row*1024 + 512 + tid], ts);
  atomicAdd(&stats[row*1024 + 768 + tid], tq);
}

// ---------------- partial max/min over n (64 rows per block)
__global__ __launch_bounds__(256) void poolpart(const float* __restrict__ maxK, const float* __restrict__ minK,
    float* __restrict__ pmax, float* __restrict__ pmin)
{
  int b = blockIdx.x, ns = blockIdx.y, c = threadIdx.x;
  float mx = -3.4e38f, mn = 3.4e38f;
  size_t base = ((size_t)b*NN + ns*64)*DD + c;
  for (int n = 0; n < 64; n++) {
    mx = fmaxf(mx, maxK[base + (size_t)n*DD]);
    mn = fminf(mn, minK[base + (size_t)n*DD]);
  }
  pmax[((size_t)b*32 + ns)*DD + c] = mx;
  pmin[((size_t)b*32 + ns)*DD + c] = mn;
}

// ---------------- final: BN2 on pooled max/min, two 256x256 linears, l2norm
__global__ __launch_bounds__(256) void finalk(const float* __restrict__ pmax, const float* __restrict__ pmin,
    const float* __restrict__ stats, const float* __restrict__ g2, const float* __restrict__ be2,
    const float* __restrict__ W1, const float* __restrict__ b1,
    const float* __restrict__ W2, const float* __restrict__ b2,
    float* __restrict__ out)
{
  __shared__ float pl[8][256];
  __shared__ float hl[8][256];
  __shared__ float nrm[8];
  int c = threadIdx.x;
  const float inv = 1.f / (float)NEDGE;
  float sm = 0.f, sq2 = 0.f;
  #pragma unroll 1
  for (int r = 0; r < NSH; r++) {
    sm  += stats[r*1024 + 512 + c];
    sq2 += stats[r*1024 + 768 + c];
  }
  float m = sm * inv;
  float var = sq2*inv - m*m;
  float s2 = g2[c] / sqrtf(var + BN_EPS);
  float t2 = be2[c] - m*s2;
  #pragma unroll
  for (int b = 0; b < 8; b++) {
    float mx = -3.4e38f, mn = 3.4e38f;
    for (int ns = 0; ns < 32; ns++) {
      mx = fmaxf(mx, pmax[((size_t)b*32+ns)*DD + c]);
      mn = fminf(mn, pmin[((size_t)b*32+ns)*DD + c]);
    }
    pl[b][c] = (s2 >= 0.f) ? s2*mx + t2 : s2*mn + t2;
  }
  __syncthreads();
  float h[8];
  #pragma unroll
  for (int b = 0; b < 8; b++) h[b] = b1[c];
  for (int k = 0; k < 256; k++) {
    float w = W1[k*256 + c];
    #pragma unroll
    for (int b = 0; b < 8; b++) h[b] += pl[b][k]*w;
  }
  __syncthreads();
  #pragma unroll
  for (int b = 0; b < 8; b++) hl[b][c] = fmaxf(h[b], 0.f);
  __syncthreads();
  float o[8];
  #pragma unroll
  for (int b = 0; b < 8; b++) o[b] = b2[c];
  for (int k = 0; k < 256; k++) {
    float w = W2[k*256 + c];
    #pragma unroll
    for (int b = 0; b < 8; b++) o[b] += hl[b][k]*w;
  }
  __syncthreads();
  #pragma unroll
  for (int b = 0; b < 8; b++) pl[b][c] = fmaxf(o[b], 0.f);
  __syncthreads();
  if (c < 8) {
    float s = 0.f;
    for (int k = 0; k < 256; k++) { float vv = pl[c][k]; s += vv*vv; }
    nrm[c] = fmaxf(sqrtf(s), 1e-12f);
  }
  __syncthreads();
  #pragma unroll
  for (int b = 0; b < 8; b++) out[b*256 + c] = pl[b][c] / nrm[b];
}

extern "C" void kernel_launch(void* const* d_in, const int* in_sizes, int n_in,
                              void* d_out, int out_size, void* d_ws, size_t ws_size,
                              hipStream_t stream) {
  (void)in_sizes; (void)n_in; (void)out_size; (void)ws_size;
  const int*   cls       = (const int*)  d_in[0];
  const float* colors    = (const float*)d_in[1];
  const float* positions = (const float*)d_in[2];
  const float* ctab      = (const float*)d_in[3];
  const float* pW1 = (const float*)d_in[4];
  const float* pb1 = (const float*)d_in[5];
  const float* pW2 = (const float*)d_in[6];
  const float* pb2 = (const float*)d_in[7];
  const float* cW1 = (const float*)d_in[8];
  const float* cb1 = (const float*)d_in[9];
  const float* cW2 = (const float*)d_in[10];
  const float* cb2 = (const float*)d_in[11];
  const float* mW  = (const float*)d_in[12];
  const float* mb  = (const float*)d_in[13];
  const float* gW1 = (const float*)d_in[14];
  const float* gb1 = (const float*)d_in[15];
  const float* gg1 = (const float*)d_in[16];
  const float* gbe1= (const float*)d_in[17];
  const float* gW2 = (const float*)d_in[18];
  const float* gb2 = (const float*)d_in[19];
  const float* gg2 = (const float*)d_in[20];
  const float* gbe2= (const float*)d_in[21];
  const float* lW1 = (const float*)d_in[22];
  const float* lb1 = (const float*)d_in[23];
  const float* lW2 = (const float*)d_in[24];
  const float* lb2 = (const float*)d_in[25];
  float* out = (float*)d_out;

  float* wsf   = (float*)d_ws;
  float* x     = wsf + OFF_X;
  float* feat  = wsf + OFF_FEAT;
  float* sq    = wsf + OFF_SQ;
  int*   idxg  = (int*)(wsf + OFF_IDX);
  float* u     = wsf + OFF_U;
  float* v     = wsf + OFF_V;
  float* Wu    = wsf + OFF_WU;
  float* W2p   = wsf + OFF_W2P;
  float* biasp = wsf + OFF_BIASP;
  float* stats = wsf + OFF_STATS;
  float* maxK  = wsf + OFF_MAXK;
  float* minK  = wsf + OFF_MINK;
  float* pmax  = wsf + OFF_PMAX;
  float* pmin  = wsf + OFF_PMIN;
  // partial kNN buffers overlay feat (dead after the merge GEMM)
  float* pdg   = feat;
  int*   pjg   = (int*)(feat + (size_t)NPTS*32);

  hipMemsetAsync(stats, 0, NSH*1024*sizeof(float), stream);

  featurize<<<NPTS, 256, 0, stream>>>(cls, colors, positions, ctab,
                                      pW1, pb1, pW2, pb2, cW1, cb1, cW2, cb2, feat);
  gemm64<768, true, true><<<dim3(NPTS/64, 4), 256, 0, stream>>>(feat, mW, mb, x);
  sqk<<<NPTS/4, 256, 0, stream>>>(x, sq);
  prep_wu<<<DD*DD/256, 256, 0, stream>>>(gW1, Wu);
  knnk<<<BB*32*4, 256, 0, stream>>>(x, sq, pdg, pjg);
  knnmerge<<<NPTS/256, 256, 0, stream>>>(pdg, pjg, idxg);
  gemm64<256, false, false><<<dim3(NPTS/64, 4), 256, 0, stream>>>(x, Wu, nullptr, u);
  gemm64<256, false, false><<<dim3(NPTS/64, 4), 256, 0, stream>>>(x, gW1 + DD*DD, nullptr, v);
  bn1stats<<<NPTS/32, 256, 0, stream>>>(u, v, idxg, gb1, stats);
  prep2<<<1, 256, 0, stream>>>(stats, gg1, gbe1, gW2, gb2, W2p, biasp);
  edgek<<<NEDGE/64, 256, 0, stream>>>(u, v, idxg, gb1, W2p, biasp, maxK, minK, stats);
  poolpart<<<dim3(BB, 32), 256, 0, stream>>>(maxK, minK, pmax, pmin);
  finalk<<<1, 256, 0, stream>>>(pmax, pmin, stats, gg2, gbe2, lW1, lb1, lW2, lb2, out);
}